// Round 5
// baseline (29511.658 us; speedup 1.0000x reference)
//
#include <hip/hip_runtime.h>
#include <cmath>
#include <cstddef>

namespace {
constexpr int kB = 32, kT = 128, kD = 512, kH = 1024, kE = 8;
constexpr int kKV = kH + kD;      // 1536
constexpr int kBlocks = 512;      // 8 experts x 64 unit-blocks (16 units each)
constexpr int kThreads = 256;     // 4 waves = 4 gates
constexpr int kLeaves = 16;
constexpr int kLeafSz = kBlocks / kLeaves;  // 32

struct Ws {
  float c[kB][kH];                // cell state
  float lx[kT][kB][kE];           // precomputed x-part logits + selb
  unsigned leaf[kLeaves * 16];    // barrier leaf counters (64B-strided)
  unsigned root;
  unsigned gen;
  unsigned pad[14];
};

__device__ __forceinline__ float sigmoidf_(float v) { return 1.0f / (1.0f + expf(-v)); }

// Two-level monotonic grid barrier (device-scope atomics; no resets -> safe
// under graph replay given counters are zeroed per launch via hipMemsetAsync).
__device__ __forceinline__ void grid_bar(Ws* ws, int bid, unsigned tgt) {
  __syncthreads();
  if (threadIdx.x == 0) {
    __threadfence();  // release h/c stores device-wide
    const unsigned v = __hip_atomic_fetch_add(&ws->leaf[(bid & (kLeaves - 1)) * 16], 1u,
                                              __ATOMIC_ACQ_REL, __HIP_MEMORY_SCOPE_AGENT) + 1u;
    if (v == (unsigned)kLeafSz * tgt) {
      const unsigned r = __hip_atomic_fetch_add(&ws->root, 1u, __ATOMIC_ACQ_REL,
                                                __HIP_MEMORY_SCOPE_AGENT) + 1u;
      if (r == (unsigned)kLeaves * tgt)
        __hip_atomic_store(&ws->gen, tgt, __ATOMIC_RELEASE, __HIP_MEMORY_SCOPE_AGENT);
    }
    while (__hip_atomic_load(&ws->gen, __ATOMIC_ACQUIRE, __HIP_MEMORY_SCOPE_AGENT) < tgt)
      __builtin_amdgcn_s_sleep(2);
    __threadfence();  // acquire: invalidate stale L1/L2 before post-barrier reads
  }
  __syncthreads();
}

// ---- gate GEMV chunk: 16 rows (gate g) x NB staged batch rows ----
template <int NB>
__device__ __forceinline__ void cell_chunk(const float* __restrict__ Wih,
                                           const float* __restrict__ Whh,
                                           const float* __restrict__ bih,
                                           const float* __restrict__ bhh,
                                           const float (*v)[kKV], float (*gl)[64],
                                           int e, int g, int j0, int lane, bool withH) {
#pragma unroll 1
  for (int grp = 0; grp < 4; ++grp) {  // 4 groups of 4 rows
    const int r0 = grp * 4;
    float4 w[4][6];
#pragma unroll
    for (int r = 0; r < 4; ++r) {
      const size_t gr = ((size_t)e * 4 + g) * kH + j0 + r0 + r;
      const float4* whp = reinterpret_cast<const float4*>(Whh + gr * kH);
      const float4* wip = reinterpret_cast<const float4*>(Wih + gr * kD);
      if (withH) {
#pragma unroll
        for (int ii = 0; ii < 4; ++ii) w[r][ii] = whp[lane + 64 * ii];
      }
#pragma unroll
      for (int ii = 0; ii < 2; ++ii) w[r][4 + ii] = wip[lane + 64 * ii];
    }
    float a[4][NB];
#pragma unroll
    for (int r = 0; r < 4; ++r)
#pragma unroll
      for (int bi = 0; bi < NB; ++bi) a[r][bi] = 0.0f;
#pragma unroll
    for (int bi = 0; bi < NB; ++bi) {
      const float4* vp = reinterpret_cast<const float4*>(&v[bi][0]);
      if (withH) {
#pragma unroll
        for (int ii = 0; ii < 4; ++ii) {
          const float4 bv = vp[lane + 64 * ii];
#pragma unroll
          for (int r = 0; r < 4; ++r)
            a[r][bi] += w[r][ii].x * bv.x + w[r][ii].y * bv.y +
                        w[r][ii].z * bv.z + w[r][ii].w * bv.w;
        }
      }
#pragma unroll
      for (int ii = 0; ii < 2; ++ii) {
        const float4 bv = vp[256 + lane + 64 * ii];
#pragma unroll
        for (int r = 0; r < 4; ++r)
          a[r][bi] += w[r][4 + ii].x * bv.x + w[r][4 + ii].y * bv.y +
                      w[r][4 + ii].z * bv.z + w[r][4 + ii].w * bv.w;
      }
    }
#pragma unroll
    for (int r = 0; r < 4; ++r)
#pragma unroll
      for (int bi = 0; bi < NB; ++bi) {
#pragma unroll
        for (int off = 32; off > 0; off >>= 1) a[r][bi] += __shfl_xor(a[r][bi], off, 64);
      }
    if (lane == 0) {
#pragma unroll
      for (int r = 0; r < 4; ++r) {
        const size_t gr = ((size_t)e * 4 + g) * kH + j0 + r0 + r;
        const float bsum = bih[gr] + bhh[gr];
#pragma unroll
        for (int bi = 0; bi < NB; ++bi) gl[bi][g * 16 + r0 + r] = a[r][bi] + bsum;
      }
    }
  }
}
}  // namespace

// Precompute x-part of selector logits (+bias): lx[t][b][e] = x[b,t]·selW[e,H:]+selb[e]
__global__ __launch_bounds__(256) void k_lx(const float* __restrict__ x,
                                            const float* __restrict__ selW,
                                            const float* __restrict__ selb, Ws* ws) {
  const int t = blockIdx.x;
  const int b = threadIdx.x >> 3, ee = threadIdx.x & 7;
  const float4* xp = reinterpret_cast<const float4*>(x + ((size_t)b * kT + t) * kD);
  const float4* wp = reinterpret_cast<const float4*>(selW + (size_t)ee * kKV + kH);
  float acc = selb[ee];
#pragma unroll 8
  for (int i = 0; i < 128; ++i) {
    const float4 xv = xp[i], wv = wp[i];
    acc += xv.x * wv.x + xv.y * wv.y + xv.z * wv.z + xv.w * wv.w;
  }
  ws->lx[t][b][ee] = acc;
}

// Persistent kernel: all 128 steps, one two-level atomic barrier per step.
// Block bid: e = bid>>6, jb = bid&63 -> units j0=jb*16..+15. Wave = gate.
__global__ __launch_bounds__(kThreads, 2) void k_rnn(
    const float* __restrict__ x, const float* __restrict__ Wih,
    const float* __restrict__ Whh, const float* __restrict__ bih,
    const float* __restrict__ bhh, const float* __restrict__ selW,
    float* __restrict__ out, Ws* __restrict__ ws) {
  const int bid = blockIdx.x;
  const int e = bid >> 6, jb = bid & 63, j0 = jb * 16;
  const int tid = threadIdx.x;
  const int g = tid >> 6, lane = tid & 63;

  __shared__ float v[8][kKV];    // 48 KB staged [h|x] for up to 8 batch rows
  __shared__ float gl[8][64];    // gates [bi][g*16+u]
  __shared__ float slog[kB][kE];
  __shared__ int ssel[kB];
  __shared__ int bl[kB];
  __shared__ int s_cnt;

  for (int t = 0; t < kT; ++t) {
    // ---- selection (replicated per block; identical FP order everywhere) ----
    if (t == 0) {
      if (tid == 0) {
        int c = 0;
        if (e == 0)
          for (int b2 = 0; b2 < kB; ++b2) bl[c++] = b2;  // step 0: expert 0
        s_cnt = c;
      }
      __syncthreads();
    } else {
      const int b = tid >> 3, ee = tid & 7;  // 256 threads = 32 rows x 8 experts
      const float4* hp = reinterpret_cast<const float4*>(out + ((size_t)b * kT + (t - 1)) * kH);
      const float4* wp = reinterpret_cast<const float4*>(selW + (size_t)ee * kKV);
      float acc = ws->lx[t][b][ee];
#pragma unroll 8
      for (int i = 0; i < 256; ++i) {  // h-part: 1024 floats
        const float4 hv = hp[i], wv = wp[i];
        acc += hv.x * wv.x + hv.y * wv.y + hv.z * wv.z + hv.w * wv.w;
      }
      slog[b][ee] = acc;
      __syncthreads();
      if (tid < kB) {
        float best = slog[tid][0];
        int bs = 0;
#pragma unroll
        for (int ee2 = 1; ee2 < kE; ++ee2) {
          const float l = slog[tid][ee2];
          if (l > best) { best = l; bs = ee2; }  // strict > == first-max (jnp.argmax)
        }
        ssel[tid] = bs;
      }
      __syncthreads();
      if (tid == 0) {
        int c = 0;
        for (int b2 = 0; b2 < kB; ++b2)
          if (ssel[b2] == e) bl[c++] = b2;
        s_cnt = c;
      }
      __syncthreads();
    }
    const int cnt = s_cnt;
    const bool withH = (t > 0);

    // ---- cell ----
#pragma unroll 1
    for (int c0 = 0; c0 < cnt; c0 += 8) {
      const int nb = (cnt - c0 < 8) ? (cnt - c0) : 8;
      for (int idx = tid; idx < nb * 384; idx += kThreads) {
        const int bi = idx / 384, i4 = idx - bi * 384;
        const int b2 = bl[c0 + bi];
        float4 vv;
        if (i4 < 256) {
          vv = withH
                   ? reinterpret_cast<const float4*>(out + ((size_t)b2 * kT + (t - 1)) * kH)[i4]
                   : make_float4(0.f, 0.f, 0.f, 0.f);
        } else {
          vv = reinterpret_cast<const float4*>(x + ((size_t)b2 * kT + t) * kD)[i4 - 256];
        }
        reinterpret_cast<float4*>(&v[bi][0])[i4] = vv;
      }
      __syncthreads();

      const int nbr = (nb >= 7) ? 8 : (nb >= 5) ? 6 : (nb >= 3) ? 4 : nb;
      switch (nbr) {
        case 1: cell_chunk<1>(Wih, Whh, bih, bhh, v, gl, e, g, j0, lane, withH); break;
        case 2: cell_chunk<2>(Wih, Whh, bih, bhh, v, gl, e, g, j0, lane, withH); break;
        case 4: cell_chunk<4>(Wih, Whh, bih, bhh, v, gl, e, g, j0, lane, withH); break;
        case 6: cell_chunk<6>(Wih, Whh, bih, bhh, v, gl, e, g, j0, lane, withH); break;
        default: cell_chunk<8>(Wih, Whh, bih, bhh, v, gl, e, g, j0, lane, withH); break;
      }
      __syncthreads();

      if (tid < nb * 16) {
        const int bi = tid >> 4, u = tid & 15;
        const int b2 = bl[c0 + bi], j = j0 + u;
        const float gi = gl[bi][0 * 16 + u];
        const float gf = gl[bi][1 * 16 + u];
        const float gg = gl[bi][2 * 16 + u];
        const float go = gl[bi][3 * 16 + u];
        const float c_old = withH ? ws->c[b2][j] : 0.0f;
        const float c_new = sigmoidf_(gf) * c_old + sigmoidf_(gi) * tanhf(gg);
        const float h_new = sigmoidf_(go) * tanhf(c_new);
        ws->c[b2][j] = c_new;
        out[((size_t)b2 * kT + t) * kH + j] = h_new;
      }
      __syncthreads();
    }

    if (t + 1 < kT) grid_bar(ws, bid, (unsigned)(t + 1));
  }
}

extern "C" void kernel_launch(void* const* d_in, const int* in_sizes, int n_in,
                              void* d_out, int out_size, void* d_ws, size_t ws_size,
                              hipStream_t stream) {
  const float* x    = (const float*)d_in[0];
  const float* Wih  = (const float*)d_in[1];
  const float* Whh  = (const float*)d_in[2];
  const float* bih  = (const float*)d_in[3];
  const float* bhh  = (const float*)d_in[4];
  const float* selW = (const float*)d_in[5];
  const float* selb = (const float*)d_in[6];
  float* out = (float*)d_out;
  Ws* ws = (Ws*)d_ws;

  // Zero barrier counters every call (ws is poisoned once before timing and
  // never re-poisoned; monotonic counters restart from 0 each launch).
  const size_t off = offsetof(Ws, leaf);
  hipMemsetAsync((char*)d_ws + off, 0, sizeof(Ws) - off, stream);
  k_lx<<<dim3(kT), dim3(256), 0, stream>>>(x, selW, selb, ws);
  k_rnn<<<dim3(kBlocks), dim3(kThreads), 0, stream>>>(x, Wih, Whh, bih, bhh, selW, out, ws);
}

// Round 6
// 16524.168 us; speedup vs baseline: 1.7860x; 1.7860x over previous
//
#include <hip/hip_runtime.h>
#include <cmath>
#include <cstddef>

namespace {
constexpr int kB = 32, kT = 128, kD = 512, kH = 1024, kE = 8;
constexpr int kKV = kH + kD;      // 1536
constexpr int kBlocks = 512;      // 8 experts x 64 unit-blocks (16 units each)
constexpr int kThreads = 256;     // 4 waves = 4 gates
constexpr int kLeaves = 16;
constexpr int kLeafSz = kBlocks / kLeaves;  // 32

struct Ws {
  float c[kB][kH];                // cell state
  float lx[kT][kB][kE];           // precomputed x-part logits + selb
  unsigned leaf[kLeaves * 16];    // barrier leaf counters (64B-strided)
  unsigned root;
  unsigned gen;
  unsigned pad[14];
};

__device__ __forceinline__ float sigmoidf_(float v) { return 1.0f / (1.0f + expf(-v)); }

// Two-level monotonic grid barrier. KEY: all atomics RELAXED (ordering drives
// cache-maintenance emission on gfx9xx — an agent-scope ACQUIRE load emits a
// buffer_inv per poll, which round 5 showed costs ~200 us/step device-wide).
// Exactly one release fence before signaling, one acquire fence after passing.
__device__ __forceinline__ void grid_bar(Ws* ws, int bid, unsigned tgt) {
  __syncthreads();
  if (threadIdx.x == 0) {
    __builtin_amdgcn_fence(__ATOMIC_RELEASE, "agent");  // wb dirty h/c once
    const unsigned v = __hip_atomic_fetch_add(&ws->leaf[(bid & (kLeaves - 1)) * 16], 1u,
                                              __ATOMIC_RELAXED, __HIP_MEMORY_SCOPE_AGENT) + 1u;
    if (v == (unsigned)kLeafSz * tgt) {
      const unsigned r = __hip_atomic_fetch_add(&ws->root, 1u, __ATOMIC_RELAXED,
                                                __HIP_MEMORY_SCOPE_AGENT) + 1u;
      if (r == (unsigned)kLeaves * tgt)
        __hip_atomic_store(&ws->gen, tgt, __ATOMIC_RELAXED, __HIP_MEMORY_SCOPE_AGENT);
    }
    while (__hip_atomic_load(&ws->gen, __ATOMIC_RELAXED, __HIP_MEMORY_SCOPE_AGENT) < tgt)
      __builtin_amdgcn_s_sleep(8);
    __builtin_amdgcn_fence(__ATOMIC_ACQUIRE, "agent");  // single inv after pass
  }
  __syncthreads();
}

// ---- gate GEMV chunk: 16 rows (gate g) x NB staged batch rows ----
template <int NB>
__device__ __forceinline__ void cell_chunk(const float* __restrict__ Wih,
                                           const float* __restrict__ Whh,
                                           const float* __restrict__ bih,
                                           const float* __restrict__ bhh,
                                           const float (*v)[kKV], float (*gl)[64],
                                           int e, int g, int j0, int lane, bool withH) {
#pragma unroll 1
  for (int grp = 0; grp < 4; ++grp) {  // 4 groups of 4 rows
    const int r0 = grp * 4;
    float4 w[4][6];
#pragma unroll
    for (int r = 0; r < 4; ++r) {
      const size_t gr = ((size_t)e * 4 + g) * kH + j0 + r0 + r;
      const float4* whp = reinterpret_cast<const float4*>(Whh + gr * kH);
      const float4* wip = reinterpret_cast<const float4*>(Wih + gr * kD);
      if (withH) {
#pragma unroll
        for (int ii = 0; ii < 4; ++ii) w[r][ii] = whp[lane + 64 * ii];
      }
#pragma unroll
      for (int ii = 0; ii < 2; ++ii) w[r][4 + ii] = wip[lane + 64 * ii];
    }
    float a[4][NB];
#pragma unroll
    for (int r = 0; r < 4; ++r)
#pragma unroll
      for (int bi = 0; bi < NB; ++bi) a[r][bi] = 0.0f;
#pragma unroll
    for (int bi = 0; bi < NB; ++bi) {
      const float4* vp = reinterpret_cast<const float4*>(&v[bi][0]);
      if (withH) {
#pragma unroll
        for (int ii = 0; ii < 4; ++ii) {
          const float4 bv = vp[lane + 64 * ii];
#pragma unroll
          for (int r = 0; r < 4; ++r)
            a[r][bi] += w[r][ii].x * bv.x + w[r][ii].y * bv.y +
                        w[r][ii].z * bv.z + w[r][ii].w * bv.w;
        }
      }
#pragma unroll
      for (int ii = 0; ii < 2; ++ii) {
        const float4 bv = vp[256 + lane + 64 * ii];
#pragma unroll
        for (int r = 0; r < 4; ++r)
          a[r][bi] += w[r][4 + ii].x * bv.x + w[r][4 + ii].y * bv.y +
                      w[r][4 + ii].z * bv.z + w[r][4 + ii].w * bv.w;
      }
    }
#pragma unroll
    for (int r = 0; r < 4; ++r)
#pragma unroll
      for (int bi = 0; bi < NB; ++bi) {
#pragma unroll
        for (int off = 32; off > 0; off >>= 1) a[r][bi] += __shfl_xor(a[r][bi], off, 64);
      }
    if (lane == 0) {
#pragma unroll
      for (int r = 0; r < 4; ++r) {
        const size_t gr = ((size_t)e * 4 + g) * kH + j0 + r0 + r;
        const float bsum = bih[gr] + bhh[gr];
#pragma unroll
        for (int bi = 0; bi < NB; ++bi) gl[bi][g * 16 + r0 + r] = a[r][bi] + bsum;
      }
    }
  }
}
}  // namespace

// Precompute x-part of selector logits (+bias): lx[t][b][e] = x[b,t]·selW[e,H:]+selb[e]
__global__ __launch_bounds__(256) void k_lx(const float* __restrict__ x,
                                            const float* __restrict__ selW,
                                            const float* __restrict__ selb, Ws* ws) {
  const int t = blockIdx.x;
  const int b = threadIdx.x >> 3, ee = threadIdx.x & 7;
  const float4* xp = reinterpret_cast<const float4*>(x + ((size_t)b * kT + t) * kD);
  const float4* wp = reinterpret_cast<const float4*>(selW + (size_t)ee * kKV + kH);
  float acc = selb[ee];
#pragma unroll 8
  for (int i = 0; i < 128; ++i) {
    const float4 xv = xp[i], wv = wp[i];
    acc += xv.x * wv.x + xv.y * wv.y + xv.z * wv.z + xv.w * wv.w;
  }
  ws->lx[t][b][ee] = acc;
}

// Persistent kernel: all 128 steps, one grid barrier per step.
// Block bid: e = bid>>6, jb = bid&63 -> units j0=jb*16..+15. Wave = gate.
__global__ __launch_bounds__(kThreads, 2) void k_rnn(
    const float* __restrict__ x, const float* __restrict__ Wih,
    const float* __restrict__ Whh, const float* __restrict__ bih,
    const float* __restrict__ bhh, const float* __restrict__ selW,
    float* __restrict__ out, Ws* __restrict__ ws) {
  const int bid = blockIdx.x;
  const int e = bid >> 6, jb = bid & 63, j0 = jb * 16;
  const int tid = threadIdx.x;
  const int g = tid >> 6, lane = tid & 63;

  __shared__ float v[8][kKV];    // 48 KB staged [h|x] for up to 8 batch rows
  __shared__ float gl[8][64];    // gates [bi][g*16+u]
  __shared__ float slog[kB][kE];
  __shared__ int ssel[kB];
  __shared__ int bl[kB];
  __shared__ int s_cnt;

  for (int t = 0; t < kT; ++t) {
    // ---- selection (replicated per block; identical FP order everywhere) ----
    if (t == 0) {
      if (tid == 0) {
        int c = 0;
        if (e == 0)
          for (int b2 = 0; b2 < kB; ++b2) bl[c++] = b2;  // step 0: expert 0
        s_cnt = c;
      }
      __syncthreads();
    } else {
      const int b = tid >> 3, ee = tid & 7;  // 256 threads = 32 rows x 8 experts
      const float4* hp = reinterpret_cast<const float4*>(out + ((size_t)b * kT + (t - 1)) * kH);
      const float4* wp = reinterpret_cast<const float4*>(selW + (size_t)ee * kKV);
      float acc = ws->lx[t][b][ee];
#pragma unroll 8
      for (int i = 0; i < 256; ++i) {  // h-part: 1024 floats
        const float4 hv = hp[i], wv = wp[i];
        acc += hv.x * wv.x + hv.y * wv.y + hv.z * wv.z + hv.w * wv.w;
      }
      slog[b][ee] = acc;
      __syncthreads();
      if (tid < kB) {
        float best = slog[tid][0];
        int bs = 0;
#pragma unroll
        for (int ee2 = 1; ee2 < kE; ++ee2) {
          const float l = slog[tid][ee2];
          if (l > best) { best = l; bs = ee2; }  // strict > == first-max (jnp.argmax)
        }
        ssel[tid] = bs;
      }
      __syncthreads();
      if (tid == 0) {
        int c = 0;
        for (int b2 = 0; b2 < kB; ++b2)
          if (ssel[b2] == e) bl[c++] = b2;
        s_cnt = c;
      }
      __syncthreads();
    }
    const int cnt = s_cnt;
    const bool withH = (t > 0);

    // ---- cell ----
#pragma unroll 1
    for (int c0 = 0; c0 < cnt; c0 += 8) {
      const int nb = (cnt - c0 < 8) ? (cnt - c0) : 8;
      for (int idx = tid; idx < nb * 384; idx += kThreads) {
        const int bi = idx / 384, i4 = idx - bi * 384;
        const int b2 = bl[c0 + bi];
        float4 vv;
        if (i4 < 256) {
          vv = withH
                   ? reinterpret_cast<const float4*>(out + ((size_t)b2 * kT + (t - 1)) * kH)[i4]
                   : make_float4(0.f, 0.f, 0.f, 0.f);
        } else {
          vv = reinterpret_cast<const float4*>(x + ((size_t)b2 * kT + t) * kD)[i4 - 256];
        }
        reinterpret_cast<float4*>(&v[bi][0])[i4] = vv;
      }
      __syncthreads();

      const int nbr = (nb >= 7) ? 8 : (nb >= 5) ? 6 : (nb >= 3) ? 4 : nb;
      switch (nbr) {
        case 1: cell_chunk<1>(Wih, Whh, bih, bhh, v, gl, e, g, j0, lane, withH); break;
        case 2: cell_chunk<2>(Wih, Whh, bih, bhh, v, gl, e, g, j0, lane, withH); break;
        case 4: cell_chunk<4>(Wih, Whh, bih, bhh, v, gl, e, g, j0, lane, withH); break;
        case 6: cell_chunk<6>(Wih, Whh, bih, bhh, v, gl, e, g, j0, lane, withH); break;
        default: cell_chunk<8>(Wih, Whh, bih, bhh, v, gl, e, g, j0, lane, withH); break;
      }
      __syncthreads();

      if (tid < nb * 16) {
        const int bi = tid >> 4, u = tid & 15;
        const int b2 = bl[c0 + bi], j = j0 + u;
        const float gi = gl[bi][0 * 16 + u];
        const float gf = gl[bi][1 * 16 + u];
        const float gg = gl[bi][2 * 16 + u];
        const float go = gl[bi][3 * 16 + u];
        const float c_old = withH ? ws->c[b2][j] : 0.0f;
        const float c_new = sigmoidf_(gf) * c_old + sigmoidf_(gi) * tanhf(gg);
        const float h_new = sigmoidf_(go) * tanhf(c_new);
        ws->c[b2][j] = c_new;
        out[((size_t)b2 * kT + t) * kH + j] = h_new;
      }
      __syncthreads();
    }

    if (t + 1 < kT) grid_bar(ws, bid, (unsigned)(t + 1));
  }
}

extern "C" void kernel_launch(void* const* d_in, const int* in_sizes, int n_in,
                              void* d_out, int out_size, void* d_ws, size_t ws_size,
                              hipStream_t stream) {
  const float* x    = (const float*)d_in[0];
  const float* Wih  = (const float*)d_in[1];
  const float* Whh  = (const float*)d_in[2];
  const float* bih  = (const float*)d_in[3];
  const float* bhh  = (const float*)d_in[4];
  const float* selW = (const float*)d_in[5];
  const float* selb = (const float*)d_in[6];
  float* out = (float*)d_out;
  Ws* ws = (Ws*)d_ws;

  // Zero barrier counters every call (monotonic counters restart per launch;
  // async memset is graph-capture-safe and replay-deterministic).
  const size_t off = offsetof(Ws, leaf);
  hipMemsetAsync((char*)d_ws + off, 0, sizeof(Ws) - off, stream);
  k_lx<<<dim3(kT), dim3(256), 0, stream>>>(x, selW, selb, ws);
  k_rnn<<<dim3(kBlocks), dim3(kThreads), 0, stream>>>(x, Wih, Whh, bih, bhh, selW, out, ws);
}